// Round 1
// baseline (289.754 us; speedup 1.0000x reference)
//
#include <hip/hip_runtime.h>

typedef unsigned short u16;
typedef __bf16 bf16x8 __attribute__((ext_vector_type(8)));
typedef float f32x4 __attribute__((ext_vector_type(4)));

static __device__ __forceinline__ u16 f2bf(float f) {
  unsigned u = __builtin_bit_cast(unsigned, f);
  u += 0x7fffu + ((u >> 16) & 1u);
  return (u16)(u >> 16);
}

static __device__ __forceinline__ void gload_lds16(const void* g, void* l) {
  __builtin_amdgcn_global_load_lds((const __attribute__((address_space(1))) unsigned int*)g,
                                   (__attribute__((address_space(3))) unsigned int*)l,
                                   16, 0, 0);
}

// ---------------------------------------------------------------------------
// fp32 -> bf16 conversion for X, Wq, Wk, Wv, Wo (one launch)
// blocks: X:0-1023, Wq:1024-2047, Wk:2048-2303, Wv:2304-2559, Wo:2560-3583
// each block converts 4096 elems
// ---------------------------------------------------------------------------
__global__ __launch_bounds__(256) void cvt_all(
    const float* __restrict__ X, const float* __restrict__ Wq, const float* __restrict__ Wk,
    const float* __restrict__ Wv, const float* __restrict__ Wo,
    u16* __restrict__ oX, u16* __restrict__ oWq, u16* __restrict__ oWk,
    u16* __restrict__ oWv, u16* __restrict__ oWo) {
  const int b = blockIdx.x;
  const float* s; u16* d; int lb;
  if (b < 1024)      { s = X;  d = oX;  lb = b; }
  else if (b < 2048) { s = Wq; d = oWq; lb = b - 1024; }
  else if (b < 2304) { s = Wk; d = oWk; lb = b - 2048; }
  else if (b < 2560) { s = Wv; d = oWv; lb = b - 2304; }
  else               { s = Wo; d = oWo; lb = b - 2560; }
  const int base = lb * 4096 + threadIdx.x * 4;
#pragma unroll
  for (int j = 0; j < 4; ++j) {
    const int off = base + j * 1024;
    float4 v = *(const float4*)(s + off);
    ushort4 u;
    u.x = f2bf(v.x); u.y = f2bf(v.y); u.z = f2bf(v.z); u.w = f2bf(v.w);
    *(ushort4*)(d + off) = u;
  }
}

// ---------------------------------------------------------------------------
// bf16 GEMM  C[M][N] = A[M][K] @ B[N][K]^T   (both row-major, B^T form)
// 128x128 tile, BK=64, 256 threads = 4 waves (2x2), each wave 64x64 via
// 4x4 frags of mfma_f32_16x16x32_bf16. global_load_lds staging with 16B-chunk
// XOR swizzle (chunk ^= row&7) to keep ds_read_b128 conflict-free.
// ROPE epilogue: cols are h*64+d, rotate-half pair (d, d+32) = frag (nf, nf+2).
// ---------------------------------------------------------------------------
template<int ROPE, int OUTF32>
__global__ __launch_bounds__(256) void gemm_bt(
    const u16* __restrict__ A, const u16* __restrict__ B, void* __restrict__ Cv,
    int M, int N, int K, float post_scale,
    const float* __restrict__ cosp, const float* __restrict__ sinp) {
  __shared__ u16 As[128 * 64];
  __shared__ u16 Bs[128 * 64];
  const int tid = threadIdx.x;
  const int lane = tid & 63, w = tid >> 6;
  const int wr = w >> 1, wc = w & 1;
  const int lr = lane & 15, lq = lane >> 4;
  const int bm = blockIdx.y << 7, bn = blockIdx.x << 7;

  f32x4 acc[4][4] = {};

  const int nK = K >> 6;
  for (int kt = 0; kt < nK; ++kt) {
    const int k0 = kt << 6;
#pragma unroll
    for (int i = 0; i < 4; ++i) {
      const int seg = (i << 2) + w;          // 0..15, uniform per wave
      const int idx = (seg << 6) + lane;     // chunk id 0..1023
      const int r = idx >> 3, c = idx & 7;
      const int cs = (c ^ (r & 7)) << 3;     // pre-swizzled source col (elems)
      gload_lds16(A + (size_t)(bm + r) * K + k0 + cs, (char*)As + seg * 1024);
      gload_lds16(B + (size_t)(bn + r) * K + k0 + cs, (char*)Bs + seg * 1024);
    }
    __syncthreads();
    bf16x8 af[2][4], bfv[2][4];
#pragma unroll
    for (int ks = 0; ks < 2; ++ks) {
#pragma unroll
      for (int f = 0; f < 4; ++f) {
        const int ra = wr * 64 + f * 16 + lr;
        const int ca = (lq + (ks << 2)) ^ (ra & 7);
        af[ks][f] = *(const bf16x8*)&As[((ra << 3) | ca) << 3];
        const int rb = wc * 64 + f * 16 + lr;
        const int cb = (lq + (ks << 2)) ^ (rb & 7);
        bfv[ks][f] = *(const bf16x8*)&Bs[((rb << 3) | cb) << 3];
      }
    }
#pragma unroll
    for (int ks = 0; ks < 2; ++ks)
#pragma unroll
      for (int mf = 0; mf < 4; ++mf)
#pragma unroll
        for (int nf = 0; nf < 4; ++nf)
          acc[mf][nf] = __builtin_amdgcn_mfma_f32_16x16x32_bf16(
              af[ks][mf], bfv[ks][nf], acc[mf][nf], 0, 0, 0);
    __syncthreads();
  }

  const int rbase = bm + wr * 64;
  const int cbase = bn + wc * 64;
  if (OUTF32) {
    float* C = (float*)Cv;
#pragma unroll
    for (int mf = 0; mf < 4; ++mf)
#pragma unroll
      for (int r = 0; r < 4; ++r) {
        const int s = rbase + mf * 16 + lq * 4 + r;
#pragma unroll
        for (int nf = 0; nf < 4; ++nf)
          C[(size_t)s * N + cbase + nf * 16 + lr] = acc[mf][nf][r];
      }
  } else if (ROPE) {
    u16* C = (u16*)Cv;
#pragma unroll
    for (int mf = 0; mf < 4; ++mf)
#pragma unroll
      for (int r = 0; r < 4; ++r) {
        const int s = rbase + mf * 16 + lq * 4 + r;
        const float* cr = cosp + s * 64;
        const float* sr = sinp + s * 64;
#pragma unroll
        for (int nf = 0; nf < 2; ++nf) {
          const int d1 = nf * 16 + lr, d2 = d1 + 32;
          const float x1 = acc[mf][nf][r], x2 = acc[mf][nf + 2][r];
          const float y1 = (x1 * cr[d1] - x2 * sr[d1]) * post_scale;
          const float y2 = (x2 * cr[d2] + x1 * sr[d2]) * post_scale;
          C[(size_t)s * N + cbase + d1] = f2bf(y1);
          C[(size_t)s * N + cbase + d2] = f2bf(y2);
        }
      }
  } else {
    u16* C = (u16*)Cv;
#pragma unroll
    for (int mf = 0; mf < 4; ++mf)
#pragma unroll
      for (int r = 0; r < 4; ++r) {
        const int s = rbase + mf * 16 + lq * 4 + r;
#pragma unroll
        for (int nf = 0; nf < 4; ++nf)
          C[(size_t)s * N + cbase + nf * 16 + lr] = f2bf(acc[mf][nf][r]);
      }
  }
}

// ---------------------------------------------------------------------------
// causal GQA flash attention. Q pre-scaled by 1/sqrt(D) and RoPE'd.
// grid (qb=S/64, h=32); 256 threads = 4 waves, each wave owns 16 q rows.
// K tile: LDS swizzled chunks via global_load_lds. V tile: transposed into
// padded LDS (stride 72). P goes through per-wave padded LDS to A-frag layout.
// ---------------------------------------------------------------------------
__global__ __launch_bounds__(256) void attn_fwd(
    const u16* __restrict__ Qb, const u16* __restrict__ Kb,
    const u16* __restrict__ Vb, u16* __restrict__ ctx) {
  __shared__ u16 Ks[64 * 64];
  __shared__ u16 Vt[64 * 72];
  __shared__ u16 Ps[4][16 * 72];
  const int qb = blockIdx.x, h = blockIdx.y, hkv = h >> 2;
  const int tid = threadIdx.x, lane = tid & 63, w = tid >> 6;
  const int lr = lane & 15, lq = lane >> 4;

  const int qrow = qb * 64 + w * 16 + lr;
  const u16* qp = Qb + (size_t)qrow * 2048 + h * 64 + lq * 8;
  const bf16x8 qf0 = *(const bf16x8*)qp;
  const bf16x8 qf1 = *(const bf16x8*)(qp + 32);

  float m_r[4] = {-1e30f, -1e30f, -1e30f, -1e30f};
  float l_r[4] = {0.f, 0.f, 0.f, 0.f};
  f32x4 o[4] = {};

  const int nt = qb + 1;
  for (int t = 0; t < nt; ++t) {
    const int kv0 = t << 6;
    // stage K (swizzled, direct-to-LDS)
#pragma unroll
    for (int i = 0; i < 2; ++i) {
      const int seg = (i << 2) + w;         // 0..7
      const int idx = (seg << 6) + lane;    // 0..511
      const int r = idx >> 3, c = idx & 7;
      gload_lds16(Kb + (size_t)(kv0 + r) * 512 + hkv * 64 + ((c ^ (r & 7)) << 3),
                  (char*)Ks + seg * 1024);
    }
    // stage V transposed (Vt[d][kv], stride 72)
#pragma unroll
    for (int i = 0; i < 2; ++i) {
      const int db = (i << 2) + w;          // 0..7
      const u16* gv = Vb + (size_t)(kv0 + lane) * 512 + hkv * 64 + (db << 3);
      uint4 vv = *(const uint4*)gv;
      const u16* pv = (const u16*)&vv;
#pragma unroll
      for (int j = 0; j < 8; ++j)
        Vt[(db * 8 + j) * 72 + lane] = pv[j];
    }
    __syncthreads();

    // scores: S(16x64) = Q(16x64) @ K^T
    f32x4 sc[4] = {};
#pragma unroll
    for (int ks = 0; ks < 2; ++ks) {
      const bf16x8 qf = ks ? qf1 : qf0;
#pragma unroll
      for (int nf = 0; nf < 4; ++nf) {
        const int rr = nf * 16 + lr;
        const int ch = (lq + (ks << 2)) ^ (rr & 7);
        const bf16x8 kf = *(const bf16x8*)&Ks[((rr << 3) | ch) << 3];
        sc[nf] = __builtin_amdgcn_mfma_f32_16x16x32_bf16(qf, kf, sc[nf], 0, 0, 0);
      }
    }
    if (t == qb) {  // diagonal: mask kj > qi
#pragma unroll
      for (int nf = 0; nf < 4; ++nf)
#pragma unroll
        for (int r = 0; r < 4; ++r)
          if (nf * 16 + lr > w * 16 + lq * 4 + r) sc[nf][r] = -1e30f;
    }
    // online softmax (rows live across 16 lanes x 4 frags)
    float pm[4];
#pragma unroll
    for (int r = 0; r < 4; ++r)
      pm[r] = fmaxf(fmaxf(sc[0][r], sc[1][r]), fmaxf(sc[2][r], sc[3][r]));
#pragma unroll
    for (int x = 1; x < 16; x <<= 1)
#pragma unroll
      for (int r = 0; r < 4; ++r)
        pm[r] = fmaxf(pm[r], __shfl_xor(pm[r], x, 64));
    float sscale[4], rs[4] = {0.f, 0.f, 0.f, 0.f};
#pragma unroll
    for (int r = 0; r < 4; ++r) {
      const float mn = fmaxf(m_r[r], pm[r]);
      sscale[r] = __expf(m_r[r] - mn);
      m_r[r] = mn;
    }
#pragma unroll
    for (int nf = 0; nf < 4; ++nf)
#pragma unroll
      for (int r = 0; r < 4; ++r) {
        const float p = __expf(sc[nf][r] - m_r[r]);
        rs[r] += p;
        Ps[w][(lq * 4 + r) * 72 + nf * 16 + lr] = f2bf(p);
      }
#pragma unroll
    for (int x = 1; x < 16; x <<= 1)
#pragma unroll
      for (int r = 0; r < 4; ++r)
        rs[r] += __shfl_xor(rs[r], x, 64);
#pragma unroll
    for (int r = 0; r < 4; ++r) l_r[r] = l_r[r] * sscale[r] + rs[r];
#pragma unroll
    for (int nf = 0; nf < 4; ++nf)
#pragma unroll
      for (int r = 0; r < 4; ++r) o[nf][r] *= sscale[r];
    // PV: O += P(16x64) @ V(64x64)
#pragma unroll
    for (int ks = 0; ks < 2; ++ks) {
      const bf16x8 pf = *(const bf16x8*)&Ps[w][lr * 72 + (ks << 5) + (lq << 3)];
#pragma unroll
      for (int nf = 0; nf < 4; ++nf) {
        const bf16x8 vf = *(const bf16x8*)&Vt[(nf * 16 + lr) * 72 + (ks << 5) + (lq << 3)];
        o[nf] = __builtin_amdgcn_mfma_f32_16x16x32_bf16(pf, vf, o[nf], 0, 0, 0);
      }
    }
    __syncthreads();
  }
  // write ctx[s][h*64+d] bf16
#pragma unroll
  for (int nf = 0; nf < 4; ++nf)
#pragma unroll
    for (int r = 0; r < 4; ++r) {
      const int s = qb * 64 + w * 16 + lq * 4 + r;
      const int d = nf * 16 + lr;
      ctx[(size_t)s * 2048 + h * 64 + d] = f2bf(o[nf][r] / l_r[r]);
    }
}

// ---------------------------------------------------------------------------
extern "C" void kernel_launch(void* const* d_in, const int* in_sizes, int n_in,
                              void* d_out, int out_size, void* d_ws, size_t ws_size,
                              hipStream_t stream) {
  const float* X    = (const float*)d_in[0];
  const float* cosp = (const float*)d_in[1];
  const float* sinp = (const float*)d_in[2];
  const float* Wq   = (const float*)d_in[3];
  const float* Wk   = (const float*)d_in[4];
  const float* Wv   = (const float*)d_in[5];
  const float* Wo   = (const float*)d_in[6];

  u16* ws  = (u16*)d_ws;                 // offsets in u16 elements
  u16* Xb  = ws;                         // 2048x2048
  u16* Wqb = ws + 4194304;               // 2048x2048
  u16* Wkb = ws + 8388608;               // 512x2048
  u16* Wvb = ws + 9437184;               // 512x2048
  u16* Wob = ws + 10485760;              // 2048x2048
  u16* Qb  = ws + 14680064;              // 2048x2048 (rope'd, * 1/8)
  u16* Kb  = ws + 18874368;              // 2048x512  (rope'd)
  u16* Vb  = ws + 19922944;              // 2048x512
  u16* Cx  = ws + 20971520;              // 2048x2048 ctx

  cvt_all<<<3584, 256, 0, stream>>>(X, Wq, Wk, Wv, Wo, Xb, Wqb, Wkb, Wvb, Wob);

  dim3 gq(16, 16), gkv(4, 16), ga(32, 32);
  gemm_bt<1, 0><<<gq, 256, 0, stream>>>(Xb, Wqb, Qb, 2048, 2048, 2048, 0.125f, cosp, sinp);
  gemm_bt<1, 0><<<gkv, 256, 0, stream>>>(Xb, Wkb, Kb, 2048, 512, 2048, 1.0f, cosp, sinp);
  gemm_bt<0, 0><<<gkv, 256, 0, stream>>>(Xb, Wvb, Vb, 2048, 512, 2048, 1.0f, nullptr, nullptr);
  attn_fwd<<<ga, 256, 0, stream>>>(Qb, Kb, Vb, Cx);
  gemm_bt<0, 1><<<gq, 256, 0, stream>>>(Cx, Wob, d_out, 2048, 2048, 2048, 1.0f, nullptr, nullptr);
}

// Round 2
// 166.262 us; speedup vs baseline: 1.7428x; 1.7428x over previous
//
#include <hip/hip_runtime.h>

typedef unsigned short u16;
typedef __bf16 bf16x8 __attribute__((ext_vector_type(8)));
typedef float f32x4 __attribute__((ext_vector_type(4)));
typedef float f32x16 __attribute__((ext_vector_type(16)));

static __device__ __forceinline__ u16 f2bf(float f) {
  unsigned u = __builtin_bit_cast(unsigned, f);
  u += 0x7fffu + ((u >> 16) & 1u);
  return (u16)(u >> 16);
}
static __device__ __forceinline__ unsigned pk2bf(float a, float b) {
  return (unsigned)f2bf(a) | ((unsigned)f2bf(b) << 16);
}

static __device__ __forceinline__ void gload_lds16(const void* g, void* l) {
  __builtin_amdgcn_global_load_lds((const __attribute__((address_space(1))) unsigned int*)g,
                                   (__attribute__((address_space(3))) unsigned int*)l,
                                   16, 0, 0);
}

// ---------------------------------------------------------------------------
// fp32 -> bf16 conversion for X, Wq, Wk, Wv, Wo (one launch)
// ---------------------------------------------------------------------------
__global__ __launch_bounds__(256) void cvt_all(
    const float* __restrict__ X, const float* __restrict__ Wq, const float* __restrict__ Wk,
    const float* __restrict__ Wv, const float* __restrict__ Wo,
    u16* __restrict__ oX, u16* __restrict__ oWq, u16* __restrict__ oWk,
    u16* __restrict__ oWv, u16* __restrict__ oWo) {
  const int b = blockIdx.x;
  const float* s; u16* d; int lb;
  if (b < 1024)      { s = X;  d = oX;  lb = b; }
  else if (b < 2048) { s = Wq; d = oWq; lb = b - 1024; }
  else if (b < 2304) { s = Wk; d = oWk; lb = b - 2048; }
  else if (b < 2560) { s = Wv; d = oWv; lb = b - 2304; }
  else               { s = Wo; d = oWo; lb = b - 2560; }
  const int base = lb * 4096 + threadIdx.x * 4;
#pragma unroll
  for (int j = 0; j < 4; ++j) {
    const int off = base + j * 1024;
    float4 v = *(const float4*)(s + off);
    ushort4 u;
    u.x = f2bf(v.x); u.y = f2bf(v.y); u.z = f2bf(v.z); u.w = f2bf(v.w);
    *(ushort4*)(d + off) = u;
  }
}

// ---------------------------------------------------------------------------
// Fused QKV GEMM over virtual N=3072: [Wq | Wk | Wv], 128x128 tiles, BK=64.
// Epilogues: Q region -> RoPE*0.125 -> Qb[s][2048]; K region -> RoPE -> Kb[s][512];
// V region -> transposed write Vt[hkv][d][s].
// ---------------------------------------------------------------------------
__global__ __launch_bounds__(256) void gemm_qkv(
    const u16* __restrict__ A, const u16* __restrict__ Bq, const u16* __restrict__ Bk,
    const u16* __restrict__ Bv, u16* __restrict__ Qb, u16* __restrict__ Kb,
    u16* __restrict__ Vt, const float* __restrict__ cosp, const float* __restrict__ sinp) {
  __shared__ u16 As[128 * 64];
  __shared__ u16 Bs[128 * 64];
  const int tid = threadIdx.x;
  const int lane = tid & 63, w = tid >> 6;
  const int wr = w >> 1, wc = w & 1;
  const int lr = lane & 15, lq = lane >> 4;
  const int bm = blockIdx.y << 7;
  const int bn = blockIdx.x << 7;
  const int K = 2048;

  const u16* Bp; int nb, region;
  if (bn < 2048)      { Bp = Bq; nb = bn;        region = 0; }
  else if (bn < 2560) { Bp = Bk; nb = bn - 2048; region = 1; }
  else                { Bp = Bv; nb = bn - 2560; region = 2; }

  f32x4 acc[4][4] = {};

  for (int kt = 0; kt < 32; ++kt) {
    const int k0 = kt << 6;
#pragma unroll
    for (int i = 0; i < 4; ++i) {
      const int seg = (i << 2) + w;
      const int idx = (seg << 6) + lane;
      const int r = idx >> 3, c = idx & 7;
      const int cs = (c ^ (r & 7)) << 3;
      gload_lds16(A + (size_t)(bm + r) * K + k0 + cs, (char*)As + seg * 1024);
      gload_lds16(Bp + (size_t)(nb + r) * K + k0 + cs, (char*)Bs + seg * 1024);
    }
    __syncthreads();
    bf16x8 af[2][4], bfv[2][4];
#pragma unroll
    for (int ks = 0; ks < 2; ++ks) {
#pragma unroll
      for (int f = 0; f < 4; ++f) {
        const int ra = wr * 64 + f * 16 + lr;
        const int ca = (lq + (ks << 2)) ^ (ra & 7);
        af[ks][f] = *(const bf16x8*)&As[((ra << 3) | ca) << 3];
        const int rb = wc * 64 + f * 16 + lr;
        const int cb = (lq + (ks << 2)) ^ (rb & 7);
        bfv[ks][f] = *(const bf16x8*)&Bs[((rb << 3) | cb) << 3];
      }
    }
#pragma unroll
    for (int ks = 0; ks < 2; ++ks)
#pragma unroll
      for (int mf = 0; mf < 4; ++mf)
#pragma unroll
        for (int nf = 0; nf < 4; ++nf)
          acc[mf][nf] = __builtin_amdgcn_mfma_f32_16x16x32_bf16(
              af[ks][mf], bfv[ks][nf], acc[mf][nf], 0, 0, 0);
    __syncthreads();
  }

  const int rbase = bm + wr * 64;
  const int cb64 = nb + wc * 64;  // 64-aligned col base within region
  if (region == 2) {
    // transposed write: Vt[hkv][d][s], pack 4 consecutive s as ushort4
    const int hkv = cb64 >> 6;
#pragma unroll
    for (int mf = 0; mf < 4; ++mf) {
      const int s0 = rbase + mf * 16 + lq * 4;
#pragma unroll
      for (int nf = 0; nf < 4; ++nf) {
        const int d = (cb64 & 63) + nf * 16 + lr;
        ushort4 st;
        st.x = f2bf(acc[mf][nf][0]); st.y = f2bf(acc[mf][nf][1]);
        st.z = f2bf(acc[mf][nf][2]); st.w = f2bf(acc[mf][nf][3]);
        *(ushort4*)&Vt[(size_t)hkv * 131072 + (size_t)d * 2048 + s0] = st;
      }
    }
  } else {
    u16* outp = region ? Kb : Qb;
    const int ldo = region ? 512 : 2048;
    const float post = region ? 1.0f : 0.125f;
#pragma unroll
    for (int mf = 0; mf < 4; ++mf)
#pragma unroll
      for (int r = 0; r < 4; ++r) {
        const int s = rbase + mf * 16 + lq * 4 + r;
        const float* cr = cosp + s * 64;
        const float* sr = sinp + s * 64;
#pragma unroll
        for (int nf = 0; nf < 2; ++nf) {
          const int d1 = nf * 16 + lr, d2 = d1 + 32;
          const float x1 = acc[mf][nf][r], x2 = acc[mf][nf + 2][r];
          const float y1 = (x1 * cr[d1] - x2 * sr[d1]) * post;
          const float y2 = (x2 * cr[d2] + x1 * sr[d2]) * post;
          outp[(size_t)s * ldo + cb64 + d1] = f2bf(y1);
          outp[(size_t)s * ldo + cb64 + d2] = f2bf(y2);
        }
      }
  }
}

// ---------------------------------------------------------------------------
// out-proj GEMM (bf16 in, f32 out), 128x128 tile, m97 structure
// ---------------------------------------------------------------------------
__global__ __launch_bounds__(256) void gemm_out(
    const u16* __restrict__ A, const u16* __restrict__ B, float* __restrict__ C,
    int M, int N, int K) {
  __shared__ u16 As[128 * 64];
  __shared__ u16 Bs[128 * 64];
  const int tid = threadIdx.x;
  const int lane = tid & 63, w = tid >> 6;
  const int wr = w >> 1, wc = w & 1;
  const int lr = lane & 15, lq = lane >> 4;
  const int bm = blockIdx.y << 7, bn = blockIdx.x << 7;

  f32x4 acc[4][4] = {};
  const int nK = K >> 6;
  for (int kt = 0; kt < nK; ++kt) {
    const int k0 = kt << 6;
#pragma unroll
    for (int i = 0; i < 4; ++i) {
      const int seg = (i << 2) + w;
      const int idx = (seg << 6) + lane;
      const int r = idx >> 3, c = idx & 7;
      const int cs = (c ^ (r & 7)) << 3;
      gload_lds16(A + (size_t)(bm + r) * K + k0 + cs, (char*)As + seg * 1024);
      gload_lds16(B + (size_t)(bn + r) * K + k0 + cs, (char*)Bs + seg * 1024);
    }
    __syncthreads();
    bf16x8 af[2][4], bfv[2][4];
#pragma unroll
    for (int ks = 0; ks < 2; ++ks) {
#pragma unroll
      for (int f = 0; f < 4; ++f) {
        const int ra = wr * 64 + f * 16 + lr;
        const int ca = (lq + (ks << 2)) ^ (ra & 7);
        af[ks][f] = *(const bf16x8*)&As[((ra << 3) | ca) << 3];
        const int rb = wc * 64 + f * 16 + lr;
        const int cb = (lq + (ks << 2)) ^ (rb & 7);
        bfv[ks][f] = *(const bf16x8*)&Bs[((rb << 3) | cb) << 3];
      }
    }
#pragma unroll
    for (int ks = 0; ks < 2; ++ks)
#pragma unroll
      for (int mf = 0; mf < 4; ++mf)
#pragma unroll
        for (int nf = 0; nf < 4; ++nf)
          acc[mf][nf] = __builtin_amdgcn_mfma_f32_16x16x32_bf16(
              af[ks][mf], bfv[ks][nf], acc[mf][nf], 0, 0, 0);
    __syncthreads();
  }
  const int rbase = bm + wr * 64;
  const int cbase = bn + wc * 64;
#pragma unroll
  for (int mf = 0; mf < 4; ++mf)
#pragma unroll
    for (int r = 0; r < 4; ++r) {
      const int s = rbase + mf * 16 + lq * 4 + r;
#pragma unroll
      for (int nf = 0; nf < 4; ++nf)
        C[(size_t)s * N + cbase + nf * 16 + lr] = acc[mf][nf][r];
    }
}

// ---------------------------------------------------------------------------
// Attention v2: swapped-QK in-register softmax, mfma_f32_32x32x16_bf16.
// grid (64 qb, 8 hkv), 256 thr = 4 independent waves. Wave owns 8 q-rows x
// 4 q-heads (GQA-packed cols: col = 8*g + r). No LDS, no barriers.
// K read from Kb[s][512] (16B frags), V from Vt[hkv][d][s] (16B frags).
// S'[kv][q] = mfma(Kfrag, Qfrag): lane holds a full score column in regs.
// qb_eff pairing (hkv&4 -> 63-qb) balances causal work per CU.
// ---------------------------------------------------------------------------
__global__ __launch_bounds__(256, 2) void attn_v2(
    const u16* __restrict__ Qb, const u16* __restrict__ Kb,
    const u16* __restrict__ Vt, u16* __restrict__ ctx) {
  const int hkv = blockIdx.y;
  const int qb = (hkv & 4) ? (63 - (int)blockIdx.x) : (int)blockIdx.x;
  const int w = threadIdx.x >> 6, lane = threadIdx.x & 63;
  const int col = lane & 31, hi = lane >> 5;
  const int g = col >> 3, r = col & 7;
  const int q0w = qb * 32 + w * 8;      // first q row of this wave
  const int qg = q0w + r;               // this lane's q row
  const int h = hkv * 4 + g;

  // Q fragments: B[k=d][col], d = 16s + 8*hi + j
  const u16* qp = Qb + (size_t)qg * 2048 + h * 64 + hi * 8;
  uint4 qf[4];
#pragma unroll
  for (int s = 0; s < 4; ++s) qf[s] = *(const uint4*)(qp + 16 * s);

  const u16* Kp = Kb + (size_t)col * 512 + hkv * 64 + hi * 8;
  const u16* Vp = Vt + (size_t)hkv * 131072 + (size_t)col * 2048 + hi * 8;

  f32x16 o0 = {}, o1 = {};
  float m = -1e30f, l = 0.f;
  const int nt = (q0w >> 6) + 1;

  for (int t = 0; t < nt; ++t) {
    const int kv0 = t << 6;
    uint4 kf[8], vf[8];
#pragma unroll
    for (int c = 0; c < 2; ++c)
#pragma unroll
      for (int s = 0; s < 4; ++s)
        kf[c * 4 + s] = *(const uint4*)(Kp + (size_t)(kv0 + 32 * c) * 512 + 16 * s);
#pragma unroll
    for (int dt = 0; dt < 2; ++dt)
#pragma unroll
      for (int s = 0; s < 4; ++s)
        vf[dt * 4 + s] = *(const uint4*)(Vp + (size_t)dt * 65536 + kv0 + 16 * s);

    f32x16 sc0 = {}, sc1 = {};
#pragma unroll
    for (int s = 0; s < 4; ++s) {
      sc0 = __builtin_amdgcn_mfma_f32_32x32x16_bf16(
          __builtin_bit_cast(bf16x8, kf[s]), __builtin_bit_cast(bf16x8, qf[s]), sc0, 0, 0, 0);
      sc1 = __builtin_amdgcn_mfma_f32_32x32x16_bf16(
          __builtin_bit_cast(bf16x8, kf[4 + s]), __builtin_bit_cast(bf16x8, qf[s]), sc1, 0, 0, 0);
    }

    if (t == nt - 1) {  // diagonal tile: mask kv_rel > q_off
      const int qoff = (q0w & 63) + r;
#pragma unroll
      for (int i = 0; i < 16; ++i) {
        const int kvr = (i & 3) + 8 * (i >> 2) + 4 * hi;
        if (kvr > qoff) sc0[i] = -1e30f;
        if (kvr + 32 > qoff) sc1[i] = -1e30f;
      }
    }

    // column max (in-lane tree + pair exchange)
    float pa = -1e30f, pb = -1e30f, pc = -1e30f, pd = -1e30f;
#pragma unroll
    for (int i = 0; i < 4; ++i) {
      pa = fmaxf(pa, fmaxf(sc0[4 * i], sc0[4 * i + 1]));
      pb = fmaxf(pb, fmaxf(sc0[4 * i + 2], sc0[4 * i + 3]));
      pc = fmaxf(pc, fmaxf(sc1[4 * i], sc1[4 * i + 1]));
      pd = fmaxf(pd, fmaxf(sc1[4 * i + 2], sc1[4 * i + 3]));
    }
    float pm = fmaxf(fmaxf(pa, pb), fmaxf(pc, pd));
    pm = fmaxf(pm, __shfl_xor(pm, 32, 64));

    if (!__all(pm - m <= 8.0f)) {  // defer-max
      const float mn = fmaxf(m, pm);
      const float al = __expf(m - mn);
      m = mn; l *= al;
#pragma unroll
      for (int i = 0; i < 16; ++i) { o0[i] *= al; o1[i] *= al; }
    }

    float p0[16], p1[16];
    float ra_ = 0.f, rb_ = 0.f, rc_ = 0.f, rd_ = 0.f;
#pragma unroll
    for (int i = 0; i < 4; ++i) {
      p0[4 * i]     = __expf(sc0[4 * i] - m);     ra_ += p0[4 * i];
      p0[4 * i + 1] = __expf(sc0[4 * i + 1] - m); rb_ += p0[4 * i + 1];
      p0[4 * i + 2] = __expf(sc0[4 * i + 2] - m); rc_ += p0[4 * i + 2];
      p0[4 * i + 3] = __expf(sc0[4 * i + 3] - m); rd_ += p0[4 * i + 3];
      p1[4 * i]     = __expf(sc1[4 * i] - m);     ra_ += p1[4 * i];
      p1[4 * i + 1] = __expf(sc1[4 * i + 1] - m); rb_ += p1[4 * i + 1];
      p1[4 * i + 2] = __expf(sc1[4 * i + 2] - m); rc_ += p1[4 * i + 2];
      p1[4 * i + 3] = __expf(sc1[4 * i + 3] - m); rd_ += p1[4 * i + 3];
    }
    float rs = (ra_ + rb_) + (rc_ + rd_);
    l += rs + __shfl_xor(rs, 32, 64);

    // pack P into bf16 words: W0[g]=kv(8g+4hi)+0,1  W1[g]=+2,3  (per c-tile)
    unsigned W0a[4], W1a[4], W0b[4], W1b[4];
#pragma unroll
    for (int gg = 0; gg < 4; ++gg) {
      W0a[gg] = pk2bf(p0[4 * gg], p0[4 * gg + 1]);
      W1a[gg] = pk2bf(p0[4 * gg + 2], p0[4 * gg + 3]);
      W0b[gg] = pk2bf(p1[4 * gg], p1[4 * gg + 1]);
      W1b[gg] = pk2bf(p1[4 * gg + 2], p1[4 * gg + 3]);
    }
    // build B-frags (kv chunks of 16) and do PV
#pragma unroll
    for (int c = 0; c < 2; ++c) {
      const unsigned* W0 = c ? W0b : W0a;
      const unsigned* W1 = c ? W1b : W1a;
#pragma unroll
      for (int G = 0; G < 2; ++G) {
        const int ga = 2 * G, gb = 2 * G + 1;
        const unsigned t0 = __shfl_xor(W0[gb], 32, 64);
        const unsigned t1 = __shfl_xor(W1[gb], 32, 64);
        const unsigned t2 = __shfl_xor(W0[ga], 32, 64);
        const unsigned t3 = __shfl_xor(W1[ga], 32, 64);
        uint4 pw;
        pw.x = hi ? t0 : W0[ga];
        pw.y = hi ? t1 : W1[ga];
        pw.z = hi ? W0[gb] : t2;
        pw.w = hi ? W1[gb] : t3;
        const bf16x8 pf = __builtin_bit_cast(bf16x8, pw);
        const int s = c * 2 + G;  // kv chunk index
        o0 = __builtin_amdgcn_mfma_f32_32x32x16_bf16(
            __builtin_bit_cast(bf16x8, vf[s]), pf, o0, 0, 0, 0);
        o1 = __builtin_amdgcn_mfma_f32_32x32x16_bf16(
            __builtin_bit_cast(bf16x8, vf[4 + s]), pf, o1, 0, 0, 0);
      }
    }
  }

  // epilogue: ctx[qg][h*64 + d], d = 8g'+j+4hi+32dt, pack 4 consecutive d
  const float linv = 1.f / l;
  u16* op = ctx + (size_t)qg * 2048 + h * 64;
#pragma unroll
  for (int gg = 0; gg < 4; ++gg) {
    ushort4 s0, s1;
    s0.x = f2bf(o0[4 * gg] * linv);     s0.y = f2bf(o0[4 * gg + 1] * linv);
    s0.z = f2bf(o0[4 * gg + 2] * linv); s0.w = f2bf(o0[4 * gg + 3] * linv);
    s1.x = f2bf(o1[4 * gg] * linv);     s1.y = f2bf(o1[4 * gg + 1] * linv);
    s1.z = f2bf(o1[4 * gg + 2] * linv); s1.w = f2bf(o1[4 * gg + 3] * linv);
    *(ushort4*)(op + 8 * gg + 4 * hi)      = s0;
    *(ushort4*)(op + 8 * gg + 4 * hi + 32) = s1;
  }
}

// ---------------------------------------------------------------------------
extern "C" void kernel_launch(void* const* d_in, const int* in_sizes, int n_in,
                              void* d_out, int out_size, void* d_ws, size_t ws_size,
                              hipStream_t stream) {
  const float* X    = (const float*)d_in[0];
  const float* cosp = (const float*)d_in[1];
  const float* sinp = (const float*)d_in[2];
  const float* Wq   = (const float*)d_in[3];
  const float* Wk   = (const float*)d_in[4];
  const float* Wv   = (const float*)d_in[5];
  const float* Wo   = (const float*)d_in[6];

  u16* ws  = (u16*)d_ws;
  u16* Xb  = ws;                         // 2048x2048
  u16* Wqb = ws + 4194304;               // 2048x2048
  u16* Wkb = ws + 8388608;               // 512x2048
  u16* Wvb = ws + 9437184;               // 512x2048
  u16* Wob = ws + 10485760;              // 2048x2048
  u16* Qb  = ws + 14680064;              // 2048x2048 (rope'd * 1/8)
  u16* Kb  = ws + 18874368;              // 2048x512  (rope'd)
  u16* Vt  = ws + 19922944;              // 8x64x2048 (V transposed per head)
  u16* Cx  = ws + 20971520;              // 2048x2048 ctx

  cvt_all<<<3584, 256, 0, stream>>>(X, Wq, Wk, Wv, Wo, Xb, Wqb, Wkb, Wvb, Wob);

  dim3 gqkv(24, 16), ga(64, 8), go(16, 16);
  gemm_qkv<<<gqkv, 256, 0, stream>>>(Xb, Wqb, Wkb, Wvb, Qb, Kb, Vt, cosp, sinp);
  attn_v2<<<ga, 256, 0, stream>>>(Qb, Kb, Vt, Cx);
  gemm_out<<<go, 256, 0, stream>>>(Cx, Wob, (float*)d_out, 2048, 2048, 2048);
}